// Round 15
// baseline (43.350 us; speedup 1.0000x reference)
//
#include <hip/hip_runtime.h>
#include <hip/hip_fp16.h>

// Modulated deformable depthwise conv, B=8 C=128 H=W=64 K=3 PAD=1 STRIDE=1.
// Round 14: fp16 LDS cells. Round 13's pipe model: 36 ds_read_b128/iter/wave
// makes the CU-shared LDS pipe the bound (~6.9K cyc vs ~1.8K VALU). Cell =
// 4 channels x half (8B) -> corner reads become ds_read_b64 (~6 vs ~12 cyc),
// halving LDS-pipe demand, conflicts, and ds_write traffic; stg halves to
// 10 regs. Cost: +16 v_cvt_f32_f16 per tap (fits under halved LDS time) and
// ~0.02-0.05 absmax error (threshold 0.215; bound ~2.4e-3 x Sum|dynw| <= 16).
// Corrective path stays exact fp32. Structure otherwise = round 13
// (margin-5 window, double buffer, 1 barrier/iter, corrective hoist).

#define BB 8
#define CC 128
#define HH 64
#define WW 64
#define HWs (HH*WW)
#define KKT 9
#define CH 16              // channels per block
#define NCG (CC/CH)        // 8
#define CPI 4              // channels per LDS cell
#define NIT (CH/CPI)       // 4
#define ROWS 4             // output rows per block
#define NHS (HH/ROWS)      // 16
#define WLO 5
#define WR  (ROWS+12)      // 16 staged rows
#define CLO 5
#define WC  74             // cols -5 .. 68
#define CELLS (WR*WC)      // 1184 cells; 8B/cell -> 9.25 KB per buffer
#define NTHR 256
#define NK  ((CELLS + NTHR - 1)/NTHR)   // 5

struct __align__(8) hcell { __half2 lo, hi; };   // channels 0,1 | 2,3

__global__ __launch_bounds__(NTHR, 2)
void mdcn_kernel(const float* __restrict__ x,
                 const float* __restrict__ offset,
                 const float* __restrict__ mask,
                 const float* __restrict__ dynw,
                 float* __restrict__ out)
{
    __shared__ hcell lds[2][CELLS];   // 18.9 KB total

    const int blk = blockIdx.x;
    const int hs = blk & (NHS - 1);
    const int cg = (blk >> 4) & (NCG - 1);
    const int b  = blk >> 7;
    const int tid = threadIdx.x;
    const int w = tid & 63;
    const int h0 = hs * ROWS;
    const int h = h0 + (tid >> 6);

    const float* xg = x + (size_t)(b * CC + cg * CH) * HWs;

    hcell stg[NK];
    #define STAGE_LOAD(XP)                                                    \
    do {                                                                      \
        const float* xp_ = (XP);                                              \
        _Pragma("unroll")                                                     \
        for (int k = 0; k < NK; ++k) {                                        \
            const int idx = tid + k * NTHR;                                   \
            float4 v = make_float4(0.f, 0.f, 0.f, 0.f);                       \
            if (idx < CELLS) {                                                \
                const int row = idx / WC;                                     \
                const int col = idx - row * WC - CLO;                         \
                const int ar  = h0 - WLO + row;                               \
                if ((unsigned)ar < (unsigned)HH &&                            \
                    (unsigned)col < (unsigned)WW) {                           \
                    const float* pp = xp_ + ar * WW + col;                    \
                    v.x = pp[0 * HWs]; v.y = pp[1 * HWs];                     \
                    v.z = pp[2 * HWs]; v.w = pp[3 * HWs];                     \
                }                                                             \
            }                                                                 \
            stg[k].lo = __float22half2_rn(make_float2(v.x, v.y));             \
            stg[k].hi = __float22half2_rn(make_float2(v.z, v.w));             \
        }                                                                     \
    } while (0)

    #define STAGE_WRITE(DST)                                                  \
    do {                                                                      \
        hcell* Lb_ = &lds[DST][0];                                            \
        _Pragma("unroll")                                                     \
        for (int k = 0; k < NK; ++k) {                                        \
            const int idx = tid + k * NTHR;                                   \
            if (idx < CELLS) Lb_[idx] = stg[k];                               \
        }                                                                     \
    } while (0)

    // prologue: stage group 0 into buf0; metadata overlaps load latency
    STAGE_LOAD(xg);

    // ---- per-tap metadata: m, dy, dx + window offset (compact) ----
    float mv[KKT], dyv[KKT], dxv[KKT];
    int   woff[KKT];
    int   badmask = 0;
    const float* offp = offset + (size_t)b * (2 * KKT) * HWs + h * WW + w;
    const float* mskp = mask   + (size_t)b * KKT * HWs       + h * WW + w;
    #pragma unroll
    for (int t = 0; t < KKT; ++t) {
        const float oy = offp[(2 * t)     * HWs];
        const float ox = offp[(2 * t + 1) * HWs];
        const float m  = mskp[t * HWs];
        const float py = (float)(h - 1 + t / 3) + oy;
        const float px = (float)(w - 1 + t % 3) + ox;
        const float fy = floorf(py), fx = floorf(px);
        const int y0 = (int)fy, x0 = (int)fx;
        dyv[t] = py - fy;
        dxv[t] = px - fx;
        const bool inwin = (y0 >= h0 - WLO) && (y0 <= h0 - WLO + WR - 2) &&
                           (x0 >= -CLO)     && (x0 <= -CLO + WC - 2);
        if (!inwin) {
            badmask |= (1 << t);
            woff[t] = 0;
            mv[t] = 0.f;               // zeroes the LDS contribution
        } else {
            woff[t] = (y0 - (h0 - WLO)) * WC + (x0 + CLO);
            mv[t] = m;                 // pads hold zeros -> no corner masks
        }
    }
    const int anybad = __any(badmask != 0);

    STAGE_WRITE(0);
    __syncthreads();

    const float* wtb  = dynw + (size_t)(b * CC + cg * CH) * KKT;
    float*       outp = out  + (size_t)(b * CC + cg * CH) * HWs + h * WW + w;

    for (int it = 0; it < NIT; ++it) {
        const float* wt = wtb + it * CPI * KKT;
        float s0 = 0.f, s1 = 0.f, s2 = 0.f, s3 = 0.f;

        // corrective path FIRST (stg not yet live; execz-skipped at runtime)
        if (anybad) {
            #pragma unroll
            for (int t = 0; t < KKT; ++t) {
                if (badmask & (1 << t)) {
                    const float oy = offp[(2 * t)     * HWs];
                    const float ox = offp[(2 * t + 1) * HWs];
                    const float m  = mskp[t * HWs];
                    const float py = (float)(h - 1 + t / 3) + oy;
                    const float px = (float)(w - 1 + t % 3) + ox;
                    const float fy = floorf(py), fx = floorf(px);
                    const float dy = py - fy, dx = px - fx;
                    const int y0 = (int)fy, x0 = (int)fx;
                    const int y1 = y0 + 1,  x1 = x0 + 1;
                    const int cy0 = min(max(y0, 0), HH - 1);
                    const int cy1 = min(max(y1, 0), HH - 1);
                    const int cx0 = min(max(x0, 0), WW - 1);
                    const int cx1 = min(max(x1, 0), WW - 1);
                    const float m00 = ((unsigned)y0 < HH && (unsigned)x0 < WW) ? 1.f : 0.f;
                    const float m01 = ((unsigned)y0 < HH && (unsigned)x1 < WW) ? 1.f : 0.f;
                    const float m10 = ((unsigned)y1 < HH && (unsigned)x0 < WW) ? 1.f : 0.f;
                    const float m11 = ((unsigned)y1 < HH && (unsigned)x1 < WW) ? 1.f : 0.f;
                    const float omdy = 1.f - dy, omdx = 1.f - dx;
                    #pragma unroll
                    for (int c = 0; c < CPI; ++c) {
                        const float* pl = xg + (size_t)(it * CPI + c) * HWs;
                        const float v = pl[cy0 * WW + cx0] * m00 * (omdy * omdx)
                                      + pl[cy0 * WW + cx1] * m01 * (omdy * dx)
                                      + pl[cy1 * WW + cx0] * m10 * (dy * omdx)
                                      + pl[cy1 * WW + cx1] * m11 * (dy * dx);
                        const float add = v * m * wt[c * KKT + t];
                        if      (c == 0) s0 += add;
                        else if (c == 1) s1 += add;
                        else if (c == 2) s2 += add;
                        else             s3 += add;
                    }
                }
            }
        }

        // prefetch next group (hidden under the tap loop)
        if (it + 1 < NIT) {
            STAGE_LOAD(xg + (size_t)(it + 1) * CPI * HWs);
        }

        const hcell* Lp = &lds[it & 1][0];
        #pragma unroll
        for (int t = 0; t < KKT; ++t) {
            const hcell c00 = Lp[woff[t]];
            const hcell c01 = Lp[woff[t] + 1];
            const hcell c10 = Lp[woff[t] + WC];
            const hcell c11 = Lp[woff[t] + WC + 1];
            const float dy = dyv[t], dx = dxv[t], m = mv[t];
            const float omdy = 1.f - dy, omdx = 1.f - dx;
            const float w00 = omdy * omdx * m, w01 = omdy * dx * m;
            const float w10 = dy * omdx * m,   w11 = dy * dx * m;
            const float2 a00 = __half22float2(c00.lo), b00 = __half22float2(c00.hi);
            const float2 a01 = __half22float2(c01.lo), b01 = __half22float2(c01.hi);
            const float2 a10 = __half22float2(c10.lo), b10 = __half22float2(c10.hi);
            const float2 a11 = __half22float2(c11.lo), b11 = __half22float2(c11.hi);
            const float v0 = a00.x * w00 + a01.x * w01 + a10.x * w10 + a11.x * w11;
            const float v1 = a00.y * w00 + a01.y * w01 + a10.y * w10 + a11.y * w11;
            const float v2 = b00.x * w00 + b01.x * w01 + b10.x * w10 + b11.x * w11;
            const float v3 = b00.y * w00 + b01.y * w01 + b10.y * w10 + b11.y * w11;
            s0 += v0 * wt[0 * KKT + t];
            s1 += v1 * wt[1 * KKT + t];
            s2 += v2 * wt[2 * KKT + t];
            s3 += v3 * wt[3 * KKT + t];
        }

        // write next group into the IDLE buffer (no pre-barrier needed)
        if (it + 1 < NIT) {
            STAGE_WRITE((it + 1) & 1);
        }

        outp[(size_t)(it * CPI + 0) * HWs] = s0;
        outp[(size_t)(it * CPI + 1) * HWs] = s1;
        outp[(size_t)(it * CPI + 2) * HWs] = s2;
        outp[(size_t)(it * CPI + 3) * HWs] = s3;

        if (it + 1 < NIT) {
            __syncthreads();   // writes visible; old buffer free for reuse
        }
    }
    #undef STAGE_LOAD
    #undef STAGE_WRITE
}

extern "C" void kernel_launch(void* const* d_in, const int* in_sizes, int n_in,
                              void* d_out, int out_size, void* d_ws, size_t ws_size,
                              hipStream_t stream) {
    const float* x      = (const float*)d_in[0];
    const float* offset = (const float*)d_in[1];
    const float* mask   = (const float*)d_in[2];
    const float* dynw   = (const float*)d_in[3];
    float* out = (float*)d_out;

    dim3 grid(BB * NCG * NHS);   // 8 * 8 * 16 = 1024 blocks
    dim3 block(NTHR);
    mdcn_kernel<<<grid, block, 0, stream>>>(x, offset, mask, dynw, out);
}